// Round 11
// baseline (305.656 us; speedup 1.0000x reference)
//
#include <hip/hip_runtime.h>
#include <stdint.h>

// Problem constants (n=6, d=1024, T=4096)
#define T_STEPS 4096
#define DDIM    1024
// covs pipeline chunking (unchanged)
#define CH      64
#define CL      64
// means pipeline chunking (halved chunks -> 2x waves for latency hiding)
#define MCH     128
#define MCL     32
#define MEAN_ELEMS ((size_t)T_STEPS * 6 * DDIM)   // 25,165,824

#define PF1 8   // km1 nmean prefetch depth (8*6=48 outstanding <= 63 vmcnt cap)
#define PF3 4   // km3 depth (loads+stores: 3*12+6=42 <= 63)

__device__ __forceinline__ float bf2f(uint16_t h){
    return __uint_as_float(((uint32_t)h) << 16);
}
__device__ __forceinline__ uint16_t f2bf(float f){   // round-to-nearest-even
    uint32_t u = __float_as_uint(f);
    uint32_t r = 0x7FFFu + ((u >> 16) & 1u);
    return (uint16_t)((u + r) >> 16);
}
// dtype-flag-aware scalar load (flag: 1 = inputs are float32, 0 = bf16)
__device__ __forceinline__ float ld(const void* p, size_t idx, bool f32){
    return f32 ? ((const float*)p)[idx] : bf2f(((const uint16_t*)p)[idx]);
}
template<bool F32>
__device__ __forceinline__ float ldn(const void* p, size_t idx){
    return F32 ? ((const float*)p)[idx] : bf2f(((const uint16_t*)p)[idx]);
}

// Per-wave dtype detect (one wave; same data every block -> deterministic).
__device__ __forceinline__ uint32_t detect_wave(const void* imean){
    const uint32_t* w = (const uint32_t*)imean;
    int good = 0;
    for (int i = (int)(threadIdx.x & 63); i < 3072; i += 64){
        float v = bf2f((uint16_t)(w[i] & 0xFFFFu));
        float a = fabsf(v);
        if (a > 1e-6f && a < 1e4f) good++;
    }
    #pragma unroll
    for (int ofs = 32; ofs >= 1; ofs >>= 1) good += __shfl_xor(good, ofs, 64);
    return (good < 2000) ? 1u : 0u;
}

// ---------------------------------------------------------------------------
// Means bodies (round-10 logic, MCL=32 steps/chunk).
// ---------------------------------------------------------------------------
template<bool F32>
__device__ __forceinline__ void km1_body(const void* __restrict__ nmean,
                                         const float* __restrict__ As,
                                         float* __restrict__ r_ws, int c, int col){
    float r[6];
    #pragma unroll
    for (int i = 0; i < 6; ++i) r[i] = 0.f;
    float pb[PF1][6];
    const size_t base = (size_t)c*MCL*6144 + col;
    #pragma unroll
    for (int p = 0; p < PF1; ++p)
        #pragma unroll
        for (int i = 0; i < 6; ++i)
            pb[p][i] = ldn<F32>(nmean, base + (size_t)p*6144 + i*DDIM);
    for (int s0 = 0; s0 < MCL; s0 += PF1){
        const bool pf = (s0 + PF1 < MCL);    // uniform
        #pragma unroll
        for (int p = 0; p < PF1; ++p){
            const int s = s0 + p;
            float n[6];
            #pragma unroll
            for (int i = 0; i < 6; ++i) n[i] = pb[p][i];
            if (pf){
                #pragma unroll
                for (int i = 0; i < 6; ++i)
                    pb[p][i] = ldn<F32>(nmean, base + (size_t)(s + PF1)*6144 + i*DDIM);
            }
            const float* A = As + s*36;      // LDS (lgkmcnt, not vmcnt)
            float acc[6];
            #pragma unroll
            for (int i = 0; i < 6; ++i){
                float t = n[i];
                #pragma unroll
                for (int m = 0; m < 6; ++m) t += A[i*6+m]*r[m];
                acc[i] = t;
            }
            #pragma unroll
            for (int i = 0; i < 6; ++i) r[i] = acc[i];
        }
    }
    float* out = r_ws + (size_t)c*6144;
    #pragma unroll
    for (int i = 0; i < 6; ++i) out[i*DDIM + col] = r[i];
}

template<bool F32>
__device__ __forceinline__ void km3_body(const void* __restrict__ nmean,
                                         const float* __restrict__ As,
                                         const float* __restrict__ mb_ws,
                                         void* __restrict__ means_out,
                                         int c, int col){
    float m[6];
    const float* mb = mb_ws + (size_t)c*6144;
    #pragma unroll
    for (int i = 0; i < 6; ++i) m[i] = mb[i*DDIM + col];
    float pb[PF3][6];
    const size_t base = (size_t)c*MCL*6144 + col;
    #pragma unroll
    for (int p = 0; p < PF3; ++p)
        #pragma unroll
        for (int i = 0; i < 6; ++i)
            pb[p][i] = ldn<F32>(nmean, base + (size_t)p*6144 + i*DDIM);
    for (int s0 = 0; s0 < MCL; s0 += PF3){
        const bool pf = (s0 + PF3 < MCL);    // uniform
        #pragma unroll
        for (int p = 0; p < PF3; ++p){
            const int s = s0 + p;
            float n[6];
            #pragma unroll
            for (int i = 0; i < 6; ++i) n[i] = pb[p][i];
            if (pf){
                #pragma unroll
                for (int i = 0; i < 6; ++i)
                    pb[p][i] = ldn<F32>(nmean, base + (size_t)(s + PF3)*6144 + i*DDIM);
            }
            const int k = c*MCL + s;
            const float* A = As + s*36;      // LDS
            float acc[6];
            #pragma unroll
            for (int i = 0; i < 6; ++i){
                float t = n[i];
                #pragma unroll
                for (int mm = 0; mm < 6; ++mm) t += A[i*6+mm]*m[mm];
                acc[i] = t;
            }
            #pragma unroll
            for (int i = 0; i < 6; ++i){
                m[i] = acc[i];
                if (F32){
                    ((float*)means_out)[(size_t)k*6144 + i*DDIM + col] = m[i];
                } else {
                    ((uint16_t*)means_out)[(size_t)k*6144 + i*DDIM + col] = f2bf(m[i]);
                }
            }
        }
    }
}

// ---------------------------------------------------------------------------
// LA = km1 (blocks 0-511: means-chunk mc=b>>2, 32 steps) + k1 compose
// (blocks 512-575: covs chunk, 64 threads active). Separate BLOCKS, same
// 256-thread bounds -> no VGPR cap on km1 (round-9 spill lesson).
// k1 additionally tracks Pm (32-step product, reset at s=32) to emit the
// 128 per-means-chunk Pf products for km2.
// ---------------------------------------------------------------------------
__global__ void __launch_bounds__(256)
LA_km1_compose(const void* __restrict__ imean, const void* __restrict__ trans,
               const void* __restrict__ ncov, const void* __restrict__ nmean,
               double* __restrict__ Pd, double* __restrict__ Qd,
               float* __restrict__ Pf, float* __restrict__ r_ws){
    __shared__ float As[CL*36], Ns[CL*36];
    __shared__ uint32_t s_flag;
    const int b = blockIdx.x;
    const int tid = threadIdx.x;
    if (tid < 64){
        uint32_t fl = detect_wave(imean);
        if (tid == 0) s_flag = fl;
    }
    __syncthreads();
    const bool f32 = s_flag != 0;

    if (b < 512){
        // ---- km1: means-chunk mc, 32 steps ----
        const int mc = b >> 2;
        for (int idx = tid; idx < MCL*36; idx += 256)
            As[idx] = ld(trans, (size_t)mc*MCL*36 + idx, f32);
        __syncthreads();
        const int col = (b & 3)*256 + tid;
        if (f32) km1_body<true >(nmean, As, r_ws, mc, col);
        else     km1_body<false>(nmean, As, r_ws, mc, col);
        return;
    }

    // ---- k1: covs chunk c, shuffle recursion (P,Q) + means products (Pm) ----
    const int c = b - 512;
    for (int idx = tid; idx < CL*36; idx += 256){
        const size_t g = (size_t)c*CL*36 + idx;
        As[idx] = ld(trans, g, f32);
        Ns[idx] = ld(ncov,  g, f32);
    }
    __syncthreads();
    if (tid >= 64) return;
    const int e  = tid;
    const int ec = (e < 36) ? e : 0;
    const int i = ec / 6, j = ec % 6;
    const int i6 = i*6, j6 = j*6;
    double P = (i == j) ? 1.0 : 0.0, Q = 0.0;
    double Pm = (i == j) ? 1.0 : 0.0;
    for (int s = 0; s < CL; ++s){
        const float* A  = As + s*36;
        const float* Nn = Ns + s*36;
        double newP = 0.0, Tij = 0.0, newPm = 0.0;
        #pragma unroll
        for (int m = 0; m < 6; ++m){
            double am = (double)A[i6+m];
            newP  += am * __shfl(P,  m*6+j, 64);   // P[m][j]
            Tij   += am * __shfl(Q,  m*6+j, 64);   // Q[m][j]
            newPm += am * __shfl(Pm, m*6+j, 64);   // Pm[m][j]
        }
        double qn = 0.0;
        #pragma unroll
        for (int m = 0; m < 6; ++m){
            qn += __shfl(Tij, i6+m, 64) * (double)A[j6+m];     // T[i][m]*A[j][m]
            qn += (double)Nn[i6+m] * (double)Nn[j6+m];         // + n n^T
        }
        P = newP; Q = qn; Pm = newPm;
        if (s == CL/2 - 1){                  // end of first 32 steps
            if (e < 36) Pf[(size_t)(2*c)*36 + e] = (float)Pm;
            Pm = (i == j) ? 1.0 : 0.0;       // restart for second half
        }
    }
    if (e < 36){
        Pd[c*36+e] = P;
        Qd[c*36+e] = Q;
        Pf[(size_t)(2*c+1)*36 + e] = (float)Pm;
    }
}

// ---------------------------------------------------------------------------
// L2 = km2 (blocks 0-3: 128 means chunks) + k2 boundary scan (block 4).
// mb_ws ALIASES r_ws: iter c writes mb[c] and prefetches r[c+4] (disjoint);
// r[c..c+3] already live in registers -> safe.
// ---------------------------------------------------------------------------
__global__ void __launch_bounds__(256)
L2_scans(const void* __restrict__ imean, const void* __restrict__ icov,
         const float* __restrict__ Pf,
         const double* __restrict__ Pd, const double* __restrict__ Qd,
         float* __restrict__ rmb_ws, double* __restrict__ Mb){
    __shared__ float  Psf[MCH*36];           // km2 stage (blocks 0-3)
    __shared__ double Psd[CH*36], Qsd[CH*36], l_ds[36];   // k2 stage (block 4)
    __shared__ uint32_t s_flag;
    const int b = blockIdx.x;
    const int tid = threadIdx.x;
    if (tid < 64){
        uint32_t fl = detect_wave(imean);
        if (tid == 0) s_flag = fl;
    }
    __syncthreads();
    const bool f32 = s_flag != 0;

    if (b < 4){
        for (int idx = tid; idx < MCH*36; idx += 256) Psf[idx] = Pf[idx];
        __syncthreads();
        const int col = b*256 + tid;
        float m[6];
        #pragma unroll
        for (int i = 0; i < 6; ++i) m[i] = ld(imean, (size_t)i*DDIM + col, f32);
        float rb[4][6];
        #pragma unroll
        for (int p = 0; p < 4; ++p)
            #pragma unroll
            for (int i = 0; i < 6; ++i) rb[p][i] = rmb_ws[(size_t)p*6144 + i*DDIM + col];
        for (int c0 = 0; c0 < MCH; c0 += 4){
            const bool pf = (c0 + 4 < MCH);  // uniform
            #pragma unroll
            for (int p = 0; p < 4; ++p){
                const int c = c0 + p;
                float rc[6];
                #pragma unroll
                for (int i = 0; i < 6; ++i) rc[i] = rb[p][i];
                if (pf){
                    #pragma unroll
                    for (int i = 0; i < 6; ++i)
                        rb[p][i] = rmb_ws[(size_t)(c+4)*6144 + i*DDIM + col];
                }
                float* mb = rmb_ws + (size_t)c*6144;   // overwrite consumed r
                #pragma unroll
                for (int i = 0; i < 6; ++i) mb[i*DDIM + col] = m[i];
                float nm[6];
                #pragma unroll
                for (int i = 0; i < 6; ++i){
                    float s0 = rc[i];
                    #pragma unroll
                    for (int mm = 0; mm < 6; ++mm) s0 += Psf[c*36 + i*6+mm]*m[mm];
                    nm[i] = s0;
                }
                #pragma unroll
                for (int i = 0; i < 6; ++i) m[i] = nm[i];
            }
        }
    } else {
        // block 4: k2 boundary scan (wave 0 shuffle recursion, 64 covs chunks)
        for (int idx = tid; idx < CH*36; idx += 256){
            Psd[idx] = Pd[idx];
            Qsd[idx] = Qd[idx];
        }
        if (tid < 36) l_ds[tid] = (double)ld(icov, tid, f32);
        __syncthreads();
        if (tid < 64){
            const int e  = tid;
            const int ec = (e < 36) ? e : 0;
            const int i = ec / 6, j = ec % 6;
            const int i6 = i*6, j6 = j*6;
            double M = 0.0;
            #pragma unroll
            for (int mm = 0; mm < 6; ++mm) M += l_ds[i6+mm] * l_ds[j6+mm];
            if (e < 36) Mb[e] = M;
            for (int cc = 0; cc < CH - 1; ++cc){
                const double* Pc = Psd + cc*36;
                double t = 0.0;
                #pragma unroll
                for (int m = 0; m < 6; ++m) t += Pc[i6+m] * __shfl(M, m*6+j, 64);
                double mn = 0.0;
                #pragma unroll
                for (int m = 0; m < 6; ++m) mn += __shfl(t, i6+m, 64) * Pc[j6+m];
                mn += Qsd[cc*36 + ec];
                M = mn;
                if (e < 36) Mb[(cc+1)*36 + e] = mn;
            }
        }
    }
}

// ---------------------------------------------------------------------------
// L3 = km3 (blocks 0-511: 128 means chunks x 32 steps) + k34 expand+QR
// (blocks 512-575: 64 covs chunks, verbatim round-10).
// ---------------------------------------------------------------------------
__global__ void __launch_bounds__(256)
L3_final(const void* __restrict__ imean, const void* __restrict__ icov,
         const void* __restrict__ trans, const void* __restrict__ ncov,
         const void* __restrict__ nmean,
         const double* __restrict__ Mb, const float* __restrict__ rmb_ws,
         void* __restrict__ d_out,
         uint32_t* __restrict__ masks, uint32_t* __restrict__ chunkTot){
    __shared__ float As[CL*36], Ns[CL*36];
    __shared__ double Mst[CL*37];            // stride 37: avoid row aliasing
    __shared__ uint32_t s_flag;
    const int b = blockIdx.x;
    const int tid = threadIdx.x;
    if (tid < 64){
        uint32_t fl = detect_wave(imean);
        if (tid == 0) s_flag = fl;
    }
    __syncthreads();
    const bool f32 = s_flag != 0;

    if (b < 512){
        // ---- km3: means-chunk mc ----
        const int mc = b >> 2;
        for (int idx = tid; idx < MCL*36; idx += 256)
            As[idx] = ld(trans, (size_t)mc*MCL*36 + idx, f32);
        __syncthreads();
        const int col = (b & 3)*256 + tid;
        if (f32) km3_body<true >(nmean, As, rmb_ws, d_out, mc, col);
        else     km3_body<false>(nmean, As, rmb_ws, d_out, mc, col);
        return;
    }

    // ---- k34: expand + QR for covs chunk c ----
    const int c = b - 512;
    for (int idx = tid; idx < CL*36; idx += 256){
        const size_t g = (size_t)c*CL*36 + idx;
        As[idx] = ld(trans, g, f32);
        Ns[idx] = ld(ncov,  g, f32);
    }
    __syncthreads();

    if (tid < 64){
        const int e  = tid;
        const int ec = (e < 36) ? e : 0;
        const int i = ec / 6, j = ec % 6;
        const int i6 = i*6, j6 = j*6;
        double M = Mb[c*36 + ec];
        for (int s = 0; ; ++s){
            if (e < 36) Mst[s*37 + e] = M;   // M entering step s
            if (s == CL - 1) break;          // uniform
            const float* A  = As + s*36;
            const float* Nn = Ns + s*36;
            double t = 0.0;
            #pragma unroll
            for (int m = 0; m < 6; ++m) t += (double)A[i6+m] * __shfl(M, m*6+j, 64);
            double mn = 0.0;
            #pragma unroll
            for (int m = 0; m < 6; ++m){
                mn += __shfl(t, i6+m, 64) * (double)A[j6+m];
                mn += (double)Nn[i6+m] * (double)Nn[j6+m];
            }
            M = mn;
        }
    }
    __syncthreads();

    if (tid >= 64) return;
    const int e = tid;
    const int k = c*CL + e;
    double X[12][6];
    if (k == 0){
        double l0[6][6], A0[6][6];
        #pragma unroll
        for (int a = 0; a < 36; ++a){
            l0[a/6][a%6] = (double)ld(icov, a, f32);
            A0[a/6][a%6] = (double)As[a];
        }
        #pragma unroll
        for (int i2 = 0; i2 < 6; ++i2)
            #pragma unroll
            for (int j2 = 0; j2 < 6; ++j2){
                double s = 0.0;
                #pragma unroll
                for (int m = 0; m < 6; ++m) s += A0[i2][m] * l0[m][j2];
                X[j2][i2] = s;               // top block = (A l)^T
            }
    } else {
        double Mx[6][6];
        #pragma unroll
        for (int a = 0; a < 36; ++a) Mx[a/6][a%6] = Mst[e*37 + a];
        // Cholesky in place
        #pragma unroll
        for (int j2 = 0; j2 < 6; ++j2){
            double d = Mx[j2][j2];
            #pragma unroll
            for (int m = 0; m < 6; ++m) if (m < j2) d -= Mx[j2][m]*Mx[j2][m];
            d = (d > 1e-300) ? d : 1e-300;
            double cjj = sqrt(d);
            Mx[j2][j2] = cjj;
            double inv = 1.0 / cjj;
            #pragma unroll
            for (int i2 = 0; i2 < 6; ++i2){
                if (i2 > j2){
                    double s = Mx[i2][j2];
                    #pragma unroll
                    for (int m = 0; m < 6; ++m) if (m < j2) s -= Mx[i2][m]*Mx[j2][m];
                    Mx[i2][j2] = s * inv;
                }
            }
        }
        #pragma unroll
        for (int i2 = 0; i2 < 6; ++i2){
            double Arow[6];
            #pragma unroll
            for (int m = 0; m < 6; ++m) Arow[m] = (double)As[e*36 + i2*6 + m];
            #pragma unroll
            for (int j2 = 0; j2 < 6; ++j2){
                double s = 0.0;
                #pragma unroll
                for (int m = 0; m < 6; ++m) if (m >= j2) s += Arow[m] * Mx[m][j2];
                X[j2][i2] = s;               // top block = (A C)^T
            }
        }
    }
    // bottom block = n^T
    #pragma unroll
    for (int r = 0; r < 6; ++r)
        #pragma unroll
        for (int c2 = 0; c2 < 6; ++c2)
            X[6+r][c2] = (double)Ns[e*36 + c2*6 + r];

    // In-place Householder QR, LAPACK sign convention
    #pragma unroll
    for (int kk = 0; kk < 6; ++kk){
        double alpha = X[kk][kk];
        double xn2 = 0.0;
        #pragma unroll
        for (int i2 = 0; i2 < 12; ++i2) if (i2 > kk) xn2 += X[i2][kk]*X[i2][kk];
        if (xn2 != 0.0){
            double nrm  = sqrt(alpha*alpha + xn2);
            double beta = (alpha >= 0.0) ? -nrm : nrm;
            double tau  = (beta - alpha) / beta;
            double sc   = 1.0 / (alpha - beta);
            #pragma unroll
            for (int i2 = 0; i2 < 12; ++i2) if (i2 > kk) X[i2][kk] *= sc;
            X[kk][kk] = beta;
            #pragma unroll
            for (int j2 = 0; j2 < 6; ++j2){
                if (j2 > kk){
                    double w = X[kk][j2];
                    #pragma unroll
                    for (int i2 = 0; i2 < 12; ++i2) if (i2 > kk) w += X[i2][kk]*X[i2][j2];
                    double wt = tau * w;
                    X[kk][j2] -= wt;
                    #pragma unroll
                    for (int i2 = 0; i2 < 12; ++i2) if (i2 > kk) X[i2][j2] -= X[i2][kk]*wt;
                }
            }
        }
    }

    uint32_t mask = 0;
    #pragma unroll
    for (int j2 = 0; j2 < 6; ++j2) if (X[j2][j2] < 0.0) mask |= (1u << j2);
    masks[k] = mask;

    // per-chunk XOR total for L4's cross-chunk prefix
    uint32_t incl = mask;
    #pragma unroll
    for (int ofs = 1; ofs < 64; ofs <<= 1){
        uint32_t up = (uint32_t)__shfl_up((int)incl, ofs, 64);
        if (e >= ofs) incl ^= up;
    }
    if (e == 63) chunkTot[c] = incl;

    if (f32){
        float* o = (float*)d_out + MEAN_ELEMS + (size_t)k*36;
        #pragma unroll
        for (int i2 = 0; i2 < 6; ++i2)
            #pragma unroll
            for (int j2 = 0; j2 < 6; ++j2)
                o[i2*6 + j2] = (j2 <= i2) ? (float)X[j2][i2] : 0.0f;
    } else {
        uint16_t* o = (uint16_t*)d_out + MEAN_ELEMS + (size_t)k*36;
        #pragma unroll
        for (int i2 = 0; i2 < 6; ++i2)
            #pragma unroll
            for (int j2 = 0; j2 < 6; ++j2)
                o[i2*6 + j2] = f2bf((j2 <= i2) ? (float)X[j2][i2] : 0.0f);
    }
}

// ---------------------------------------------------------------------------
// L4 = k56: cross-chunk sign prefix + apply (covs chunking unchanged).
// ---------------------------------------------------------------------------
__global__ void __launch_bounds__(64)
L4_sign_apply(const void* __restrict__ imean,
              void* __restrict__ d_out,
              const uint32_t* __restrict__ masks,
              const uint32_t* __restrict__ chunkTot){
    __shared__ uint32_t s_flag;
    const int c = blockIdx.x;
    const int e = threadIdx.x;
    {
        uint32_t fl = detect_wave(imean);
        if (e == 0) s_flag = fl;
    }
    __syncthreads();
    const bool f32 = s_flag != 0;
    const int k = c*CL + e;
    const uint32_t m = masks[k];
    uint32_t incl = m;
    #pragma unroll
    for (int ofs = 1; ofs < 64; ofs <<= 1){
        uint32_t up = (uint32_t)__shfl_up((int)incl, ofs, 64);
        if (e >= ofs) incl ^= up;
    }
    const uint32_t excl = incl ^ m;
    uint32_t v = (e < c) ? chunkTot[e] : 0u;   // c<=63 -> lanes 0..62 suffice
    #pragma unroll
    for (int ofs = 32; ofs >= 1; ofs >>= 1) v ^= (uint32_t)__shfl_xor((int)v, ofs, 64);
    const uint32_t am = v ^ excl;              // == old amask[k]
    if (am == 0u) return;
    if (f32){
        uint32_t* o = (uint32_t*)d_out + MEAN_ELEMS + (size_t)k*36;
        #pragma unroll
        for (int t = 0; t < 36; ++t)
            if ((am >> (t % 6)) & 1u) o[t] ^= 0x80000000u;
    } else {
        uint16_t* o = (uint16_t*)d_out + MEAN_ELEMS + (size_t)k*36;
        #pragma unroll
        for (int t = 0; t < 36; ++t)
            if ((am >> (t % 6)) & 1u) o[t] ^= 0x8000u;
    }
}

// ---------------------------------------------------------------------------
extern "C" void kernel_launch(void* const* d_in, const int* in_sizes, int n_in,
                              void* d_out, int out_size, void* d_ws, size_t ws_size,
                              hipStream_t stream){
    (void)in_sizes; (void)n_in; (void)out_size; (void)ws_size;
    const void* imean = d_in[0];  // [6,1024]
    const void* icov  = d_in[1];  // [6,6]
    const void* trans = d_in[2];  // [T,6,6]
    const void* nmean = d_in[3];  // [T,6,1024]
    const void* ncov  = d_in[4];  // [T,6,6]

    // workspace layout (8-byte types first; ~3.3 MB total)
    char* w = (char*)d_ws;
    double* Pd   = (double*)w; w += (size_t)CH*36*8;
    double* Qd   = (double*)w; w += (size_t)CH*36*8;
    double* Mb   = (double*)w; w += (size_t)CH*36*8;
    float*  Pf   = (float*)w;  w += (size_t)MCH*36*4;
    uint32_t* masks    = (uint32_t*)w; w += (size_t)T_STEPS*4;
    uint32_t* chunkTot = (uint32_t*)w; w += (size_t)CH*4;
    float* rmb_ws = (float*)w; w += (size_t)MCH*6*DDIM*4;   // r_ws, then mb_ws

    LA_km1_compose<<<512 + CH, 256, 0, stream>>>(imean, trans, ncov, nmean,
                                                 Pd, Qd, Pf, rmb_ws);
    L2_scans<<<5, 256, 0, stream>>>(imean, icov, Pf, Pd, Qd, rmb_ws, Mb);
    L3_final<<<512 + CH, 256, 0, stream>>>(imean, icov, trans, ncov, nmean,
                                           Mb, rmb_ws, d_out, masks, chunkTot);
    L4_sign_apply<<<CH, 64, 0, stream>>>(imean, d_out, masks, chunkTot);
}